// Round 12
// baseline (54.591 us; speedup 1.0000x reference)
//
#include <hip/hip_runtime.h>

// Problem constants
#define N_  32
#define C_  32
#define H_  56
#define W_  56
#define O_  32
#define HP_ 58   // padded
#define WP_ 58
#define HW_ (H_*W_)          // 3136
#define CHW_ (C_*H_*W_)      // 100352
#define KK_ 9
#define CKK_ (C_*KK_)        // 288

// xT layout: [C][HP][WP][N] (zero padded border), bf16
#define XT_ELEMS ((size_t)C_*HP_*WP_*N_)

#define KP_   144   // k-pairs (288/2)
#define PSTR_ 36    // uints per kp-row: 32 n + 4 pad

typedef __bf16 bf16x8 __attribute__((ext_vector_type(8)));
typedef float  f32x4  __attribute__((ext_vector_type(4)));

// -------- transpose + pad + bf16-convert:  x[N][C][H][W] -> xT[C][HP][WP][N] --------
__global__ __launch_bounds__(256) void xpose_kernel(const float* __restrict__ x,
                                                    __bf16* __restrict__ xT) {
    const int c = blockIdx.x;   // 0..31
    const int y = blockIdx.y;   // 0..57 (padded row)
    __shared__ float sb[32 * 57];
    const int tid = threadIdx.x;
    const bool interior = (y >= 1) && (y <= H_);
    if (interior) {
        for (int idx = tid; idx < N_ * W_; idx += 256) {
            int n = idx / W_;
            int col = idx - n * W_;
            sb[n * 57 + col] = x[((size_t)(n * C_ + c) * H_ + (y - 1)) * W_ + col];
        }
    }
    __syncthreads();
    __bf16* dst = xT + ((size_t)(c * HP_ + y)) * WP_ * N_;
    for (int idx = tid; idx < WP_ * N_; idx += 256) {
        int xx = idx >> 5;
        int n  = idx & 31;
        float v = 0.f;
        if (interior && xx >= 1 && xx <= W_) v = sb[n * 57 + (xx - 1)];
        dst[idx] = (__bf16)v;
    }
}

// -------- MFMA main --------
// MAX-TLP variant: block = ONE position, 4 quadrant waves (nh x oh), LDS =
// P2 only (20.7 KB -> ~7 blocks/CU by LDS), ONE barrier. Grid 3136. Per-wave
// work is tiny (5 build loads + 18 weight float4 + 36 ds_read_b32 + 9 MFMA),
// so per-CU block-level overlap (~6-7 deep) hides the L2/L3 latency chains
// that capped every low-TLP structure (r8/r9/r10/r11 post-mortems).
// Numerics identical to r6 (same P2 build per position, same MFMA fragments).
__global__ __launch_bounds__(256) void lc2d_mfma(const float* __restrict__ wgt,
                                                 const __bf16* __restrict__ xT,
                                                 const float* __restrict__ bias,
                                                 float* __restrict__ out) {
    __shared__ unsigned P2[KP_ * PSTR_];              // 20736 B

    const int tid = threadIdx.x;

    // bijective XCD-chunk swizzle: 3136 blocks = 8 XCDs x 392 consecutive wg ids
    const int flat = blockIdx.x;
    const int wg = (flat & 7) * 392 + (flat >> 3);
    const int w = wg % 56;
    const int h = wg / 56;
    const int pos = h * W_ + w;

    // ---- build P2 (coalesced, arithmetic offsets): 576 tasks ----
    {
        const __bf16* xbase = xT + (h * WP_ + w) * N_;
        #pragma unroll
        for (int it = 0; it < 3; ++it) {
            const int task = it * 256 + tid;
            if (it < 2 || task < 576) {
                const int kp = task >> 2;
                const int g  = task & 3;
                const int k0 = 2 * kp, k1 = 2 * kp + 1;
                const int c0 = k0 / 9, ij0 = k0 - 9 * c0;
                const int i0 = ij0 / 3, j0 = ij0 - 3 * i0;
                const int c1 = k1 / 9, ij1 = k1 - 9 * c1;
                const int i1 = ij1 / 3, j1 = ij1 - 3 * i1;
                const int off0 = c0 * (HP_ * WP_ * N_) + i0 * (WP_ * N_) + j0 * N_;
                const int off1 = c1 * (HP_ * WP_ * N_) + i1 * (WP_ * N_) + j1 * N_;
                union { uint4 qv; ushort sv[8]; } ua, ub;
                ua.qv = *(const uint4*)(xbase + off0 + 8 * g);
                ub.qv = *(const uint4*)(xbase + off1 + 8 * g);
                unsigned o0[8];
                #pragma unroll
                for (int m = 0; m < 8; ++m)
                    o0[m] = (unsigned)ua.sv[m] | ((unsigned)ub.sv[m] << 16);
                unsigned* dst = &P2[kp * PSTR_ + 8 * g];
                *(uint4*)(dst)     = make_uint4(o0[0], o0[1], o0[2], o0[3]);
                *(uint4*)(dst + 4) = make_uint4(o0[4], o0[5], o0[6], o0[7]);
            }
        }
    }
    __syncthreads();

    // ---- MFMA: wave = (nh, oh) quadrant, 9 k-steps, 1 MFMA/step ----
    const int wave = tid >> 6;       // 0..3
    const int lane = tid & 63;
    const int nh = wave & 1;         // n-half
    const int oh = wave >> 1;        // o-half
    const int q = lane >> 4;         // k-group 0..3
    const int r = lane & 15;         // o (B-frag) / n (A-frag) within tile

    const int o = oh * 16 + r;
    const float* wb = wgt + ((size_t)(o * HW_ + pos)) * CKK_ + 8 * q;
    const unsigned* pa = &P2[(4 * q) * PSTR_ + nh * 16 + r];

    const float bv = bias[o * HW_ + pos];
    f32x4 acc = {bv, bv, bv, bv};

    #pragma unroll
    for (int s = 0; s < 9; ++s) {
        union { unsigned u[4]; bf16x8 v; } a0;
        #pragma unroll
        for (int d = 0; d < 4; ++d)
            a0.u[d] = pa[(16 * s + d) * PSTR_];
        const float4 ba = *(const float4*)(wb + 32 * s);
        const float4 bb = *(const float4*)(wb + 32 * s + 4);
        bf16x8 bfB;
        bfB[0] = (__bf16)ba.x; bfB[1] = (__bf16)ba.y; bfB[2] = (__bf16)ba.z; bfB[3] = (__bf16)ba.w;
        bfB[4] = (__bf16)bb.x; bfB[5] = (__bf16)bb.y; bfB[6] = (__bf16)bb.z; bfB[7] = (__bf16)bb.w;
        acc = __builtin_amdgcn_mfma_f32_16x16x32_bf16(a0.v, bfB, acc, 0, 0, 0);
    }

    // ---- direct scattered stores (L2 write-merge verified r9/r10) ----
    #pragma unroll
    for (int reg = 0; reg < 4; ++reg) {
        const int n = nh * 16 + q * 4 + reg;
        out[(size_t)n * CHW_ + o * HW_ + pos] = acc[reg];
    }
}

// -------- fallback (if workspace too small): thread per output, bounds-checked --------
__global__ __launch_bounds__(256) void lc2d_naive(const float* __restrict__ x,
                                                  const float* __restrict__ wgt,
                                                  const float* __restrict__ bias,
                                                  float* __restrict__ out) {
    int idx = blockIdx.x * 256 + threadIdx.x;
    const int total = N_ * O_ * H_ * W_;
    if (idx >= total) return;
    int w = idx % W_;
    int h = (idx / W_) % H_;
    int o = (idx / HW_) % O_;
    int n = idx / CHW_;
    const float* wp = wgt + ((size_t)((o * H_ + h) * W_ + w)) * CKK_;
    float s = 0.f;
    for (int c = 0; c < C_; ++c) {
        for (int i = 0; i < 3; ++i) {
            int yy = h + i - 1;
            if (yy < 0 || yy >= H_) continue;
            for (int j = 0; j < 3; ++j) {
                int xx = w + j - 1;
                if (xx < 0 || xx >= W_) continue;
                s = fmaf(wp[c * KK_ + i * 3 + j],
                         x[((size_t)(n * C_ + c) * H_ + yy) * W_ + xx], s);
            }
        }
    }
    out[idx] = s + bias[idx % CHW_];
}

extern "C" void kernel_launch(void* const* d_in, const int* in_sizes, int n_in,
                              void* d_out, int out_size, void* d_ws, size_t ws_size,
                              hipStream_t stream) {
    const float* x    = (const float*)d_in[0];
    const float* wgt  = (const float*)d_in[1];
    const float* bias = (const float*)d_in[2];
    float* out = (float*)d_out;

    const size_t need = XT_ELEMS * sizeof(__bf16);
    if (ws_size >= need) {
        __bf16* xT = (__bf16*)d_ws;
        hipLaunchKernelGGL(xpose_kernel, dim3(C_, HP_), dim3(256), 0, stream, x, xT);
        hipLaunchKernelGGL(lc2d_mfma, dim3(3136), dim3(256), 0, stream, wgt, xT, bias, out);
    } else {
        int total = N_ * O_ * H_ * W_;
        hipLaunchKernelGGL(lc2d_naive, dim3((total + 255) / 256), dim3(256), 0, stream,
                           x, wgt, bias, out);
    }
}

// Round 13
// 41.588 us; speedup vs baseline: 1.3127x; 1.3127x over previous
//
#include <hip/hip_runtime.h>

// Problem constants
#define N_  32
#define C_  32
#define H_  56
#define W_  56
#define O_  32
#define HP_ 58   // padded
#define WP_ 58
#define HW_ (H_*W_)          // 3136
#define CHW_ (C_*H_*W_)      // 100352
#define KK_ 9
#define CKK_ (C_*KK_)        // 288

// xT layout: [C][HP][WP][N] (zero padded border), bf16
#define XT_ELEMS ((size_t)C_*HP_*WP_*N_)

#define KP_   144   // k-pairs (288/2)
#define PSTR_ 36    // uints per kp-row: 32 n + 4 pad

typedef __bf16 bf16x8 __attribute__((ext_vector_type(8)));
typedef float  f32x4  __attribute__((ext_vector_type(4)));

// -------- transpose + pad + bf16-convert:  x[N][C][H][W] -> xT[C][HP][WP][N] --------
__global__ __launch_bounds__(256) void xpose_kernel(const float* __restrict__ x,
                                                    __bf16* __restrict__ xT) {
    const int c = blockIdx.x;   // 0..31
    const int y = blockIdx.y;   // 0..57 (padded row)
    __shared__ float sbuf[32 * 57];   // [n][col], row stride 57
    const int tid = threadIdx.x;
    const bool interior = (y >= 1) && (y <= H_);
    if (interior) {
        for (int idx = tid; idx < N_ * W_; idx += 256) {
            int n = idx / W_;
            int col = idx - n * W_;
            sbuf[n * 57 + col] = x[((size_t)(n * C_ + c) * H_ + (y - 1)) * W_ + col];
        }
    }
    __syncthreads();
    __bf16* dst = xT + ((size_t)(c * HP_ + y)) * WP_ * N_;
    for (int idx = tid; idx < WP_ * N_; idx += 256) {
        int xx = idx >> 5;        // 0..57
        int n  = idx & 31;
        float v = 0.f;
        if (interior && xx >= 1 && xx <= W_) v = sbuf[n * 57 + (xx - 1)];
        dst[idx] = (__bf16)v;
    }
}

// -------- MFMA main --------
// r13 = r7 kernel with ONE change: __launch_bounds__(256, 4) -> VGPR cap 128
// (4 waves/SIMD, 16 waves/CU). r7's hoisted wv[18] (72 VGPR) could never stay
// live under the default ~64-VGPR occupancy target (r4/r12: VGPR 28/52 =>
// serialized weight loads, 51/66 us). With 128 VGPR the 18 weight loads + 9
// build loads are all in flight concurrently per wave: ~2 latency waits per
// block instead of ~9, at HIGHER TLP than r6.
// Weight read-once invariant preserved (wave = (dw, oh), both n-halves inside).
__global__ __launch_bounds__(256, 4) void lc2d_mfma(const float* __restrict__ wgt,
                                                    const __bf16* __restrict__ xT,
                                                    const float* __restrict__ bias,
                                                    float* __restrict__ out) {
    __shared__ unsigned P2[2 * KP_ * PSTR_];          // 41472 B
    __shared__ __align__(16) float sbuf[32][33][2];   // 8448 B

    const int tid = threadIdx.x;

    // bijective XCD-chunk swizzle: 1568 blocks = 8 XCDs x 196 consecutive wg ids
    const int flat = blockIdx.x;
    const int wg = (flat & 7) * 196 + (flat >> 3);
    const int wt = wg % 28;          // w-tile of 2
    const int h  = wg / 28;          // 0..55
    const int w0 = wt * 2;

    const int wave = tid >> 6;       // 0..3
    const int lane = tid & 63;
    const int dw = wave & 1;         // which w of the pair
    const int oh = wave >> 1;        // which o-half
    const int w  = w0 + dw;
    const int q = lane >> 4;         // k-group 0..3
    const int r = lane & 15;         // o (B-frag) / n (A-frag) within tile

    // ---- issue ALL weight loads first (o = oh*16 + r, full k-range) ----
    const float* wb = wgt + ((size_t)((oh * 16 + r) * HW_ + h * W_ + w)) * CKK_ + 8 * q;
    float4 wv[18];
    #pragma unroll
    for (int s = 0; s < 9; ++s) {
        wv[2 * s]     = *(const float4*)(wb + 32 * s);
        wv[2 * s + 1] = *(const float4*)(wb + 32 * s + 4);
    }
    __builtin_amdgcn_sched_barrier(0);   // don't let these sink below the build

    // ---- build P2 (coalesced, offsets arithmetic): task = dw*576 + kp*4 + g ----
    const __bf16* xbase = xT + (h * WP_ + w0) * N_;
    #pragma unroll
    for (int it = 0; it < 5; ++it) {
        const int task = it * 256 + tid;
        if (task < 1152) {
            const int tdw = task / 576;
            const int rem = task - tdw * 576;
            const int kp  = rem >> 2;
            const int g   = rem & 3;
            const int k0 = 2 * kp, k1 = 2 * kp + 1;
            const int c0 = k0 / 9, ij0 = k0 - 9 * c0;
            const int i0 = ij0 / 3, j0 = ij0 - 3 * i0;
            const int c1 = k1 / 9, ij1 = k1 - 9 * c1;
            const int i1 = ij1 / 3, j1 = ij1 - 3 * i1;
            const int off0 = c0 * (HP_ * WP_ * N_) + i0 * (WP_ * N_) + j0 * N_;
            const int off1 = c1 * (HP_ * WP_ * N_) + i1 * (WP_ * N_) + j1 * N_;
            const __bf16* s0 = xbase + tdw * N_ + off0 + 8 * g;
            const __bf16* s1 = xbase + tdw * N_ + off1 + 8 * g;
            union { uint4 qv; ushort sv[8]; } ua, ub;
            ua.qv = *(const uint4*)s0;
            ub.qv = *(const uint4*)s1;
            unsigned o0[8];
            #pragma unroll
            for (int m = 0; m < 8; ++m)
                o0[m] = (unsigned)ua.sv[m] | ((unsigned)ub.sv[m] << 16);
            unsigned* dst = &P2[(tdw * KP_ + kp) * PSTR_ + 8 * g];
            *(uint4*)(dst)     = make_uint4(o0[0], o0[1], o0[2], o0[3]);
            *(uint4*)(dst + 4) = make_uint4(o0[4], o0[5], o0[6], o0[7]);
        }
    }
    __syncthreads();

    // A base in LDS: kp = 4q (+16 rows per step, +1 row per k-pair), n = r
    const unsigned* pa = &P2[(dw * KP_ + 4 * q) * PSTR_ + r];

    f32x4 acc0 = {0.f, 0.f, 0.f, 0.f};   // n 0..15
    f32x4 acc1 = {0.f, 0.f, 0.f, 0.f};   // n 16..31

    #pragma unroll
    for (int s = 0; s < 9; ++s) {
        union { unsigned u[4]; bf16x8 v; } a0, a1;
        #pragma unroll
        for (int d = 0; d < 4; ++d) {
            a0.u[d] = pa[s * (16 * PSTR_) + d * PSTR_];        // n = r
            a1.u[d] = pa[s * (16 * PSTR_) + d * PSTR_ + 16];   // n = r+16
        }
        const float4 ba = wv[2 * s];
        const float4 bb = wv[2 * s + 1];
        bf16x8 bfB;
        bfB[0] = (__bf16)ba.x; bfB[1] = (__bf16)ba.y; bfB[2] = (__bf16)ba.z; bfB[3] = (__bf16)ba.w;
        bfB[4] = (__bf16)bb.x; bfB[5] = (__bf16)bb.y; bfB[6] = (__bf16)bb.z; bfB[7] = (__bf16)bb.w;

        acc0 = __builtin_amdgcn_mfma_f32_16x16x32_bf16(a0.v, bfB, acc0, 0, 0, 0);
        acc1 = __builtin_amdgcn_mfma_f32_16x16x32_bf16(a1.v, bfB, acc1, 0, 0, 0);
    }

    // stage C into LDS: n = mt*16 + q*4 + reg, o = oh*16 + r (layout verified round 2)
    #pragma unroll
    for (int mt = 0; mt < 2; ++mt) {
        f32x4 a = mt == 0 ? acc0 : acc1;
        const int o = oh * 16 + r;
        #pragma unroll
        for (int reg = 0; reg < 4; ++reg) {
            const int n = mt * 16 + q * 4 + reg;
            sbuf[n][o][dw] = a[reg];
        }
    }
    __syncthreads();

    // store: float2 over {w0, w0+1} per (n,o), + bias
    #pragma unroll
    for (int rr = 0; rr < 4; ++rr) {
        const int fl = rr * 256 + tid;   // 0..1023 -> (n,o)
        const int n = fl >> 5;
        const int o = fl & 31;
        float2 v = *(const float2*)&sbuf[n][o][0];
        const float2 bv = *(const float2*)(bias + o * HW_ + h * W_ + w0);
        v.x += bv.x; v.y += bv.y;
        *(float2*)(out + (size_t)n * CHW_ + o * HW_ + h * W_ + w0) = v;
    }
}

// -------- fallback (if workspace too small): thread per output, bounds-checked --------
__global__ __launch_bounds__(256) void lc2d_naive(const float* __restrict__ x,
                                                  const float* __restrict__ wgt,
                                                  const float* __restrict__ bias,
                                                  float* __restrict__ out) {
    int idx = blockIdx.x * 256 + threadIdx.x;
    const int total = N_ * O_ * H_ * W_;
    if (idx >= total) return;
    int w = idx % W_;
    int h = (idx / W_) % H_;
    int o = (idx / HW_) % O_;
    int n = idx / CHW_;
    const float* wp = wgt + ((size_t)((o * H_ + h) * W_ + w)) * CKK_;
    float s = 0.f;
    for (int c = 0; c < C_; ++c) {
        for (int i = 0; i < 3; ++i) {
            int yy = h + i - 1;
            if (yy < 0 || yy >= H_) continue;
            for (int j = 0; j < 3; ++j) {
                int xx = w + j - 1;
                if (xx < 0 || xx >= W_) continue;
                s = fmaf(wp[c * KK_ + i * 3 + j],
                         x[((size_t)(n * C_ + c) * H_ + yy) * W_ + xx], s);
            }
        }
    }
    out[idx] = s + bias[idx % CHW_];
}

extern "C" void kernel_launch(void* const* d_in, const int* in_sizes, int n_in,
                              void* d_out, int out_size, void* d_ws, size_t ws_size,
                              hipStream_t stream) {
    const float* x    = (const float*)d_in[0];
    const float* wgt  = (const float*)d_in[1];
    const float* bias = (const float*)d_in[2];
    float* out = (float*)d_out;

    const size_t need = XT_ELEMS * sizeof(__bf16);
    if (ws_size >= need) {
        __bf16* xT = (__bf16*)d_ws;
        hipLaunchKernelGGL(xpose_kernel, dim3(C_, HP_), dim3(256), 0, stream, x, xT);
        hipLaunchKernelGGL(lc2d_mfma, dim3(1568), dim3(256), 0, stream, wgt, xT, bias, out);
    } else {
        int total = N_ * O_ * H_ * W_;
        hipLaunchKernelGGL(lc2d_naive, dim3((total + 255) / 256), dim3(256), 0, stream,
                           x, wgt, bias, out);
    }
}